// Round 2
// baseline (614.957 us; speedup 1.0000x reference)
//
#include <hip/hip_runtime.h>

#define H 4096
#define O 4096
#define HO 8192
#define MAXLEN 15

// wave (64-lane) dot product: fp32 row x fp32 vector, K multiple of 256
__device__ __forceinline__ float wave_dot(const float* __restrict__ w,
                                          const float* __restrict__ x,
                                          int K, int lane) {
    const float4* w4 = (const float4*)w;
    const float4* x4 = (const float4*)x;
    float acc = 0.f;
    int n4 = K >> 2;
    for (int i = lane; i < n4; i += 64) {
        float4 wv = w4[i];
        float4 xv = x4[i];
        acc += wv.x * xv.x + wv.y * xv.y + wv.z * xv.z + wv.w * xv.w;
    }
    #pragma unroll
    for (int off = 32; off; off >>= 1) acc += __shfl_down(acc, off, 64);
    return acc;
}

// K1: emb lookup + attention logits + softmax + att_applied -> combined
__global__ void k_att(const int* __restrict__ ids,
                      const float* __restrict__ hidden,
                      const float* __restrict__ eseq,
                      const float* __restrict__ embW,
                      const float* __restrict__ attW,
                      const float* __restrict__ attb,
                      float* __restrict__ combined,
                      float* __restrict__ out_attw) {
    __shared__ float s_logit[MAXLEN];
    __shared__ float s_w[MAXLEN];
    const int tid  = threadIdx.x;
    const int wave = tid >> 6, lane = tid & 63;
    const int id = ids[0];
    const float* emb = embW + (size_t)id * O;

    // combined[0:O] = emb
    for (int k = tid; k < O; k += blockDim.x) combined[k] = emb[k];

    if (wave < MAXLEN) {
        const float* wrow = attW + (size_t)wave * (H + O);
        float acc = 0.f;
        for (int t = lane; t < O; t += 64) acc += emb[t] * wrow[t];
        for (int t = lane; t < H; t += 64) acc += hidden[t] * wrow[O + t];
        #pragma unroll
        for (int off = 32; off; off >>= 1) acc += __shfl_down(acc, off, 64);
        if (lane == 0) s_logit[wave] = acc + attb[wave];
    }
    __syncthreads();
    if (tid == 0) {
        float m = -1e30f;
        for (int j = 0; j < MAXLEN; j++) m = fmaxf(m, s_logit[j]);
        float s = 0.f;
        for (int j = 0; j < MAXLEN; j++) { float e = __expf(s_logit[j] - m); s_w[j] = e; s += e; }
        float inv = 1.f / s;
        for (int j = 0; j < MAXLEN; j++) { s_w[j] *= inv; out_attw[j] = s_w[j]; }
    }
    __syncthreads();
    // combined[O:O+H] = att_weights @ e_output_seq
    for (int k = tid; k < H; k += blockDim.x) {
        float acc = 0.f;
        #pragma unroll
        for (int j = 0; j < MAXLEN; j++) acc += s_w[j] * eseq[j * H + k];
        combined[O + k] = acc;
    }
}

// K2: fused x = relu(comb_W @ combined + b)  and  gh = gru_W_hh @ h0 + b_hh
__global__ void k_comb_ghh(const float* __restrict__ combW,
                           const float* __restrict__ combB,
                           const float* __restrict__ ghhW,
                           const float* __restrict__ ghhB,
                           const float* __restrict__ hidden,
                           const float* __restrict__ combined,
                           float* __restrict__ xout,
                           float* __restrict__ ghout) {
    const int wave = threadIdx.x >> 6, lane = threadIdx.x & 63;
    const int b = blockIdx.x;
    if (b < 1024) {
        int row = b * 4 + wave;               // 0..4095
        float d = wave_dot(combW + (size_t)row * HO, combined, HO, lane);
        if (lane == 0) xout[row] = fmaxf(d + combB[row], 0.f);
    } else {
        int row = (b - 1024) * 4 + wave;      // 0..12287
        float d = wave_dot(ghhW + (size_t)row * H, hidden, H, lane);
        if (lane == 0) ghout[row] = d + ghhB[row];
    }
}

// K3: gi = gru_W_ih @ x, gate math, h_new
__global__ void k_gru(const float* __restrict__ gihW,
                      const float* __restrict__ gihB,
                      const float* __restrict__ hidden,
                      const float* __restrict__ x,
                      const float* __restrict__ gh,
                      float* __restrict__ hout,
                      float* __restrict__ out_h) {
    const int wave = threadIdx.x >> 6, lane = threadIdx.x & 63;
    const int i = blockIdx.x * 4 + wave;      // 0..4095
    float d0 = wave_dot(gihW + (size_t)i * H,           x, H, lane);
    float d1 = wave_dot(gihW + (size_t)(i + H) * H,     x, H, lane);
    float d2 = wave_dot(gihW + (size_t)(i + 2 * H) * H, x, H, lane);
    if (lane == 0) {
        float ir = d0 + gihB[i];
        float iz = d1 + gihB[i + H];
        float in_ = d2 + gihB[i + 2 * H];
        float hr = gh[i], hz = gh[i + H], hn = gh[i + 2 * H];
        float r = 1.f / (1.f + __expf(-(ir + hr)));
        float z = 1.f / (1.f + __expf(-(iz + hz)));
        float n = tanhf(in_ + r * hn);
        float h0 = hidden[i];
        float h = (1.f - z) * n + z * h0;
        hout[i] = h;
        out_h[i] = h;
    }
}

// K4: logits = out_W @ h_new + out_b
__global__ void k_out(const float* __restrict__ outW,
                      const float* __restrict__ outB,
                      const float* __restrict__ h,
                      float* __restrict__ logits) {
    const int wave = threadIdx.x >> 6, lane = threadIdx.x & 63;
    const int i = blockIdx.x * 4 + wave;
    float d = wave_dot(outW + (size_t)i * H, h, H, lane);
    if (lane == 0) logits[i] = d + outB[i];
}

// K5: log_softmax over 4096 logits
__global__ void k_lsm(const float* __restrict__ logits, float* __restrict__ out) {
    __shared__ float red[16];
    __shared__ float red2[16];
    const int tid = threadIdx.x, lane = tid & 63, wave = tid >> 6;
    float m = -1e30f;
    for (int k = tid; k < O; k += 1024) m = fmaxf(m, logits[k]);
    #pragma unroll
    for (int off = 32; off; off >>= 1) m = fmaxf(m, __shfl_down(m, off, 64));
    if (lane == 0) red[wave] = m;
    __syncthreads();
    if (tid == 0) {
        float mm = -1e30f;
        for (int j = 0; j < 16; j++) mm = fmaxf(mm, red[j]);
        red[0] = mm;
    }
    __syncthreads();
    m = red[0];
    float s = 0.f;
    for (int k = tid; k < O; k += 1024) s += __expf(logits[k] - m);
    #pragma unroll
    for (int off = 32; off; off >>= 1) s += __shfl_down(s, off, 64);
    if (lane == 0) red2[wave] = s;
    __syncthreads();
    if (tid == 0) {
        float ss = 0.f;
        for (int j = 0; j < 16; j++) ss += red2[j];
        red2[0] = m + logf(ss);
    }
    __syncthreads();
    float lse = red2[0];
    for (int k = tid; k < O; k += 1024) out[k] = logits[k] - lse;
}

extern "C" void kernel_launch(void* const* d_in, const int* in_sizes, int n_in,
                              void* d_out, int out_size, void* d_ws, size_t ws_size,
                              hipStream_t stream) {
    const int*   ids    = (const int*)d_in[0];
    const float* hidden = (const float*)d_in[1];
    // d_in[2] (e_output) unused by the reference
    const float* eseq   = (const float*)d_in[3];
    const float* embW   = (const float*)d_in[4];
    const float* attW   = (const float*)d_in[5];
    const float* attb   = (const float*)d_in[6];
    const float* combW  = (const float*)d_in[7];
    const float* combB  = (const float*)d_in[8];
    const float* gihW   = (const float*)d_in[9];
    const float* ghhW   = (const float*)d_in[10];
    const float* gihB   = (const float*)d_in[11];
    const float* ghhB   = (const float*)d_in[12];
    const float* outW   = (const float*)d_in[13];
    const float* outB   = (const float*)d_in[14];
    float* out = (float*)d_out;   // [log_softmax(4096) | h_new(4096) | att_w(15)]

    float* ws       = (float*)d_ws;
    float* combined = ws;             // 8192
    float* xbuf     = ws + 8192;      // 4096
    float* ghbuf    = ws + 12288;     // 12288
    float* hbuf     = ws + 24576;     // 4096
    float* logits   = ws + 28672;     // 4096

    k_att     <<<1,    960,  0, stream>>>(ids, hidden, eseq, embW, attW, attb, combined, out + 8192);
    k_comb_ghh<<<4096, 256,  0, stream>>>(combW, combB, ghhW, ghhB, hidden, combined, xbuf, ghbuf);
    k_gru     <<<1024, 256,  0, stream>>>(gihW, gihB, hidden, xbuf, ghbuf, hbuf, out + 4096);
    k_out     <<<1024, 256,  0, stream>>>(outW, outB, hbuf, logits);
    k_lsm     <<<1,    1024, 0, stream>>>(logits, out);
}